// Round 13
// baseline (172.585 us; speedup 1.0000x reference)
//
#include <hip/hip_runtime.h>
#include <hip/hip_bf16.h>

#define N_NODES 50000
#define FDIM 128
#define NPAD 50176      // 49 * 1024, covers N_NODES+1
#define SCAN_NB 49

typedef short bf16x8 __attribute__((ext_vector_type(8)));
typedef float f32x4  __attribute__((ext_vector_type(4)));

__device__ __forceinline__ unsigned short rne_bf16(float f) {
    unsigned int u = __float_as_uint(f);
    unsigned int r = (u + 0x7FFFu + ((u >> 16) & 1u)) >> 16;
    return (unsigned short)r;
}
__device__ __forceinline__ float bf16_to_f32(unsigned short s) {
    return __uint_as_float(((unsigned int)s) << 16);
}
__device__ __forceinline__ void split_bf16(float f, unsigned short& h, unsigned short& l) {
    h = rne_bf16(f);
    l = rne_bf16(f - bf16_to_f32(h));
}
__device__ __forceinline__ void unpack2(unsigned int d, float& f0, float& f1) {
    f0 = __uint_as_float(d << 16);
    f1 = __uint_as_float(d & 0xFFFF0000u);
}

// ---------------------------------------------------------------------------
// Fused: blocks [0,49) zero counts; blocks [49,113) split/transpose W
// (pre-swizzled idx ^= (n&7)<<3 for LDS bank-conflict-free reads)
// ---------------------------------------------------------------------------
__global__ __launch_bounds__(256) void zero_cvtw_kernel(int4* __restrict__ counts4,
                                                        const float* __restrict__ W1,
                                                        const float* __restrict__ Wmu,
                                                        const float* __restrict__ Wlog,
                                                        unsigned short* __restrict__ W1thi,
                                                        unsigned short* __restrict__ W1tlo,
                                                        unsigned short* __restrict__ Wcthi,
                                                        unsigned short* __restrict__ Wctlo) {
    int b = blockIdx.x;
    if (b < SCAN_NB) {
        int i = b * 256 + threadIdx.x;
        if (i < NPAD / 4) counts4[i] = make_int4(0, 0, 0, 0);
        return;
    }
    int tid = (b - SCAN_NB) * 256 + threadIdx.x;   // 0..16383
    int n = tid & 127, k = tid >> 7;
    int swzidx = (n * 128 + k) ^ ((n & 7) << 3);
    unsigned short h, l;
    float v1 = W1[k * 128 + n];
    split_bf16(v1, h, l);
    W1thi[swzidx] = h;
    W1tlo[swzidx] = l;
    float v2 = (n < 64) ? Wmu[k * 64 + n] : Wlog[k * 64 + (n - 64)];
    split_bf16(v2, h, l);
    Wcthi[swzidx] = h;
    Wctlo[swzidx] = l;
}

// CSR build: count in-degree AND capture each edge's rank within its dst
__global__ __launch_bounds__(256) void count_kernel(const int* __restrict__ dst,
                                                    int* __restrict__ counts,
                                                    int* __restrict__ rank, int E) {
    int e = blockIdx.x * blockDim.x + threadIdx.x;
    if (e < E) rank[e] = atomicAdd(&counts[dst[e]], 1);
}

// local scan over PADDED counts ((c+3)&~3) + dinv (0 for idx >= N)
__global__ __launch_bounds__(256) void scan_local_kernel(const int* __restrict__ counts,
                                                         int* __restrict__ local,
                                                         int* __restrict__ bsums,
                                                         float* __restrict__ dinv) {
    int t    = threadIdx.x;
    int lane = t & 63;
    int wid  = t >> 6;
    int base = blockIdx.x * 1024 + t * 4;
    int4 c = *(const int4*)(counts + base);
    float4 dv;
    dv.x = (base + 0 < N_NODES) ? rsqrtf((float)c.x + 1.0f) : 0.f;
    dv.y = (base + 1 < N_NODES) ? rsqrtf((float)c.y + 1.0f) : 0.f;
    dv.z = (base + 2 < N_NODES) ? rsqrtf((float)c.z + 1.0f) : 0.f;
    dv.w = (base + 3 < N_NODES) ? rsqrtf((float)c.w + 1.0f) : 0.f;
    *(float4*)(dinv + base) = dv;
    int4 v;   // padded counts
    v.x = (c.x + 3) & ~3;
    v.y = (c.y + 3) & ~3;
    v.z = (c.z + 3) & ~3;
    v.w = (c.w + 3) & ~3;
    int s = v.x + v.y + v.z + v.w;
    int incl = s;
#pragma unroll
    for (int off = 1; off < 64; off <<= 1) {
        int u = __shfl_up(incl, off, 64);
        if (lane >= off) incl += u;
    }
    __shared__ int wtot[4];
    if (lane == 63) wtot[wid] = incl;
    __syncthreads();
    int wbase = 0;
#pragma unroll
    for (int w = 0; w < 3; w++) wbase += (w < wid) ? wtot[w] : 0;
    int excl = wbase + incl - s;
    int4 o;
    o.x = excl;
    o.y = excl + v.x;
    o.z = o.y + v.y;
    o.w = o.z + v.z;
    *(int4*)(local + base) = o;
    if (t == 255) bsums[blockIdx.x] = wbase + incl;
}

// fused: bsums wave-scan + add block offset + write offsets + fill CSR pad
// slots with sentinel N_NODES + zero sentinel rows of xb/Hb (block 0)
__global__ __launch_bounds__(256) void scan_add_kernel(const int* __restrict__ local,
                                                       const int* __restrict__ bsums,
                                                       const int* __restrict__ counts,
                                                       int* __restrict__ offsets,
                                                       int* __restrict__ csr_src,
                                                       unsigned short* __restrict__ xb,
                                                       unsigned short* __restrict__ Hb) {
    int t = threadIdx.x;
    __shared__ int s_bo;
    if (t < 64) {
        int v = (t < blockIdx.x) ? bsums[t] : 0;   // blockIdx <= 48 < 64
#pragma unroll
        for (int off = 32; off; off >>= 1) v += __shfl_down(v, off, 64);
        if (t == 0) s_bo = v;
    }
    // zero sentinel row N of xb and Hb (128 ushorts = 64 uints each)
    if (blockIdx.x == 0 && t >= 64 && t < 128) {
        int k = t - 64;
        ((unsigned int*)(xb + (size_t)N_NODES * 128))[k] = 0u;
        ((unsigned int*)(Hb + (size_t)N_NODES * 128))[k] = 0u;
    }
    __syncthreads();
    int bo = s_bo;
    int base = blockIdx.x * 1024 + t * 4;
    int4 v = *(const int4*)(local + base);
    int4 c = *(const int4*)(counts + base);
    v.x += bo; v.y += bo; v.z += bo; v.w += bo;
    *(int4*)(offsets + base) = v;
    // pad fill: slots [off + count, off + paddedcount) = sentinel
    int off0[4] = {v.x, v.y, v.z, v.w};
    int cr[4]   = {c.x, c.y, c.z, c.w};
#pragma unroll
    for (int k = 0; k < 4; k++) {
        int b = off0[k] + cr[k];
        int e = off0[k] + ((cr[k] + 3) & ~3);
        for (int j = b; j < e; j++) csr_src[j] = N_NODES;
    }
}

// ---------------------------------------------------------------------------
// Fused: blocks [0,scb) atomic-free scatter; blocks [scb, scb+cvb) cvt_x
// (xs = dinv[row]*x, single bf16 rounding)
// ---------------------------------------------------------------------------
__global__ __launch_bounds__(256) void scatter_cvtx_kernel(const int* __restrict__ src,
                                                           const int* __restrict__ dst,
                                                           const int* __restrict__ rank,
                                                           const int* __restrict__ offsets,
                                                           int* __restrict__ csr_src, int E,
                                                           int scb,
                                                           const float* __restrict__ x,
                                                           const float* __restrict__ dinv,
                                                           unsigned short* __restrict__ xb,
                                                           int n4) {
    int b = blockIdx.x;
    if (b < scb) {
        int e = b * 256 + threadIdx.x;
        if (e < E) {
            int d = dst[e];
            int pos = offsets[d] + rank[e];
            csr_src[pos] = src[e];
        }
        return;
    }
    int i = (b - scb) * 256 + threadIdx.x;
    if (i >= n4) return;
    float dv = dinv[i >> 5];   // 32 float4 per row
    float4 v = ((const float4*)x)[i];
    v.x *= dv; v.y *= dv; v.z *= dv; v.w *= dv;
    unsigned int d0 = (unsigned int)rne_bf16(v.x) | ((unsigned int)rne_bf16(v.y) << 16);
    unsigned int d1 = (unsigned int)rne_bf16(v.z) | ((unsigned int)rne_bf16(v.w) << 16);
    ((uint2*)xb)[i] = make_uint2(d0, d1);
}

// ---------------------------------------------------------------------------
// COLUMN-SPLIT aggregation: 4 colgroups x 32 cols (64 B quarter-rows).
// Gather working set per colgroup = 50k x 64 B = 3.2 MB < 4 MB per-XCD L2;
// blocks ordered colgroup-major so co-resident blocks share the working set.
// Quarter-wave (16 lanes x 4 B) per node; int4 index loads (CSR 4-padded,
// sentinel row N_NODES zeroed). Same per-output summation order as before.
// ---------------------------------------------------------------------------
__global__ __launch_bounds__(256) void agg_bf16_col_kernel(const unsigned short* __restrict__ X,
                                                           const int* __restrict__ offsets,
                                                           const int* __restrict__ csr_src,
                                                           const float* __restrict__ dinv,
                                                           unsigned short* __restrict__ Y,
                                                           int n, int nb_per_g) {
    int b  = blockIdx.x;
    int g  = b / nb_per_g;                       // colgroup 0..3 (phased)
    int nb = b - g * nb_per_g;
    int node = (nb << 4) + (threadIdx.x >> 4);
    int l16  = threadIdx.x & 15;
    if (node >= n) return;
    const unsigned int* Xu = (const unsigned int*)X;   // row = 64 uints
    int coff = g * 16 + l16;                     // uint index within row

    float a0, a1;
    {
        unsigned int s = Xu[(size_t)node * 64 + coff];   // self (pre-scaled)
        unpack2(s, a0, a1);
    }

    int beg = offsets[node], end = offsets[node + 1];
    int i = beg;
    for (; i + 8 <= end; i += 8) {
        int4 q0 = *(const int4*)(csr_src + i);
        int4 q1 = *(const int4*)(csr_src + i + 4);
        unsigned int m0 = Xu[(size_t)q0.x * 64 + coff];
        unsigned int m1 = Xu[(size_t)q0.y * 64 + coff];
        unsigned int m2 = Xu[(size_t)q0.z * 64 + coff];
        unsigned int m3 = Xu[(size_t)q0.w * 64 + coff];
        unsigned int m4 = Xu[(size_t)q1.x * 64 + coff];
        unsigned int m5 = Xu[(size_t)q1.y * 64 + coff];
        unsigned int m6 = Xu[(size_t)q1.z * 64 + coff];
        unsigned int m7 = Xu[(size_t)q1.w * 64 + coff];
        float f0, f1;
        unpack2(m0, f0, f1); a0 += f0; a1 += f1;
        unpack2(m1, f0, f1); a0 += f0; a1 += f1;
        unpack2(m2, f0, f1); a0 += f0; a1 += f1;
        unpack2(m3, f0, f1); a0 += f0; a1 += f1;
        unpack2(m4, f0, f1); a0 += f0; a1 += f1;
        unpack2(m5, f0, f1); a0 += f0; a1 += f1;
        unpack2(m6, f0, f1); a0 += f0; a1 += f1;
        unpack2(m7, f0, f1); a0 += f0; a1 += f1;
    }
    if (i < end) {
        int4 q0 = *(const int4*)(csr_src + i);
        unsigned int m0 = Xu[(size_t)q0.x * 64 + coff];
        unsigned int m1 = Xu[(size_t)q0.y * 64 + coff];
        unsigned int m2 = Xu[(size_t)q0.z * 64 + coff];
        unsigned int m3 = Xu[(size_t)q0.w * 64 + coff];
        float f0, f1;
        unpack2(m0, f0, f1); a0 += f0; a1 += f1;
        unpack2(m1, f0, f1); a0 += f0; a1 += f1;
        unpack2(m2, f0, f1); a0 += f0; a1 += f1;
        unpack2(m3, f0, f1); a0 += f0; a1 += f1;
    }

    float dv = dinv[node];
    unsigned int o = (unsigned int)rne_bf16(a0 * dv) | ((unsigned int)rne_bf16(a1 * dv) << 16);
    ((unsigned int*)Y)[(size_t)node * 64 + coff] = o;
}

// ---------------------------------------------------------------------------
// MFMA GEMM, W-in-LDS: 512 threads / 8 waves / 128 rows per block.
// A single bf16; W hi/lo split -> D = A*Wh + A*Wl (fp32 accumulate).
// EPI 0: Hb = bf16(dinv[r] * relu(D + b1))   (pre-scaled for agg2)
// EPI 1: split mu/logstd halves to out.
// ---------------------------------------------------------------------------
template <int EPI>
__global__ __launch_bounds__(512) void mfma_gemm_kernel(const unsigned short* __restrict__ A,
                                                        const unsigned short* __restrict__ Wthi,
                                                        const unsigned short* __restrict__ Wtlo,
                                                        const float* __restrict__ ba,
                                                        const float* __restrict__ bb,
                                                        const float* __restrict__ dinv,
                                                        unsigned short* __restrict__ H,
                                                        float* __restrict__ out, int M) {
    __shared__ unsigned short Wlds[32768];   // hi [0,16K) ushorts, lo [16K,32K)

    int t    = threadIdx.x;
    int wave = t >> 6;
    int lane = t & 63;
    int m16  = lane & 15;
    int kg   = lane >> 4;

    // stage W (linear; source is pre-swizzled). 4096 uint4 / 512 threads.
    {
        const uint4* gh = (const uint4*)Wthi;
        const uint4* gl = (const uint4*)Wtlo;
        uint4* lds4 = (uint4*)Wlds;
#pragma unroll
        for (int i = 0; i < 4; i++) lds4[i * 512 + t] = gh[i * 512 + t];
#pragma unroll
        for (int i = 0; i < 4; i++) lds4[2048 + i * 512 + t] = gl[i * 512 + t];
    }

    int rbase = blockIdx.x * 128 + wave * 16;
    int arow  = rbase + m16;
    bool rok  = arow < M;
    const unsigned short* ar = A + (size_t)(rok ? arow : 0) * 128;
    bf16x8 af[4];
#pragma unroll
    for (int kt = 0; kt < 4; kt++) {
        bf16x8 v = *(const bf16x8*)(const void*)(ar + kt * 32 + kg * 8);
        af[kt] = rok ? v : (bf16x8)(short)0;
    }
    // per-lane output rows are rbase+kg*4+0..3 for all col tiles; hoist dinv
    float4 dv4 = {1.f, 1.f, 1.f, 1.f};
    if (EPI == 0) dv4 = *(const float4*)(dinv + rbase + kg * 4);
    __syncthreads();

    int swz = (m16 & 7) << 3;
#pragma unroll
    for (int np = 0; np < 4; np++) {
        int nt0 = np * 2, nt1 = np * 2 + 1;
        f32x4 acc0 = {0.f, 0.f, 0.f, 0.f};
        f32x4 acc1 = {0.f, 0.f, 0.f, 0.f};
#pragma unroll
        for (int kt = 0; kt < 4; kt++) {
            int i0 = (((nt0 * 16 + m16) * 128) + kt * 32 + kg * 8) ^ swz;
            int i1 = (((nt1 * 16 + m16) * 128) + kt * 32 + kg * 8) ^ swz;
            bf16x8 bh0 = *(const bf16x8*)(const void*)&Wlds[i0];
            bf16x8 bl0 = *(const bf16x8*)(const void*)&Wlds[16384 + i0];
            bf16x8 bh1 = *(const bf16x8*)(const void*)&Wlds[i1];
            bf16x8 bl1 = *(const bf16x8*)(const void*)&Wlds[16384 + i1];
            acc0 = __builtin_amdgcn_mfma_f32_16x16x32_bf16(af[kt], bh0, acc0, 0, 0, 0);
            acc1 = __builtin_amdgcn_mfma_f32_16x16x32_bf16(af[kt], bh1, acc1, 0, 0, 0);
            acc0 = __builtin_amdgcn_mfma_f32_16x16x32_bf16(af[kt], bl0, acc0, 0, 0, 0);
            acc1 = __builtin_amdgcn_mfma_f32_16x16x32_bf16(af[kt], bl1, acc1, 0, 0, 0);
        }
#pragma unroll
        for (int half = 0; half < 2; half++) {
            int nt = half ? nt1 : nt0;
            const f32x4& acc = half ? acc1 : acc0;
            int n0 = nt * 16 + m16;
            if (EPI == 0) {
                float b = ba[n0];
#pragma unroll
                for (int j = 0; j < 4; j++) {
                    int r = rbase + kg * 4 + j;
                    if (r < M) {
                        float v = fmaxf(acc[j] + b, 0.f) * dv4[j];
                        H[(size_t)r * 128 + n0] = rne_bf16(v);
                    }
                }
            } else {
                bool is_mu = (n0 < 64);
                int c = is_mu ? n0 : (n0 - 64);
                float b = is_mu ? ba[c] : bb[c];
                size_t obase = is_mu ? 0 : (size_t)N_NODES * 64;
#pragma unroll
                for (int j = 0; j < 4; j++) {
                    int r = rbase + kg * 4 + j;
                    if (r < M) out[obase + (size_t)r * 64 + c] = acc[j] + b;
                }
            }
        }
    }
}

// ---------------------------------------------------------------------------
extern "C" void kernel_launch(void* const* d_in, const int* in_sizes, int n_in,
                              void* d_out, int out_size, void* d_ws, size_t ws_size,
                              hipStream_t stream) {
    const float* x    = (const float*)d_in[0];
    const int*   ei   = (const int*)d_in[1];
    const float* W1   = (const float*)d_in[2];
    const float* b1   = (const float*)d_in[3];
    const float* Wmu  = (const float*)d_in[4];
    const float* bmu  = (const float*)d_in[5];
    const float* Wlog = (const float*)d_in[6];
    const float* blog = (const float*)d_in[7];
    float* out = (float*)d_out;

    const int N = N_NODES;
    const int E = in_sizes[1] / 2;
    const int Emax = E + 3 * N;   // CSR with 4-padding slack
    const int* src = ei;
    const int* dst = ei + E;

    auto align256 = [](size_t v) { return (v + 255) & ~(size_t)255; };
    char* ws = (char*)d_ws;
    size_t off = 0;
    int*   counts  = (int*)(ws + off);  off += align256((size_t)NPAD * 4);
    int*   offsets = (int*)(ws + off);  off += align256((size_t)NPAD * 4);
    int*   local   = (int*)(ws + off);  off += align256((size_t)NPAD * 4);
    int*   bsums   = (int*)(ws + off);  off += align256(256 * 4);
    float* dinv    = (float*)(ws + off); off += align256((size_t)NPAD * 4);
    int*   rank    = (int*)(ws + off);  off += align256((size_t)E * 4);
    int*   csr_src = (int*)(ws + off);  off += align256((size_t)Emax * 4);
    unsigned short* xb    = (unsigned short*)(ws + off); off += align256((size_t)(N + 1) * FDIM * 2);
    unsigned short* Hb    = (unsigned short*)(ws + off); off += align256((size_t)(N + 1) * FDIM * 2);
    unsigned short* Ag    = (unsigned short*)(ws + off); off += align256((size_t)N * FDIM * 2);
    unsigned short* W1thi = (unsigned short*)(ws + off); off += align256(128 * 128 * 2);
    unsigned short* W1tlo = (unsigned short*)(ws + off); off += align256(128 * 128 * 2);
    unsigned short* Wcthi = (unsigned short*)(ws + off); off += align256(128 * 128 * 2);
    unsigned short* Wctlo = (unsigned short*)(ws + off); off += align256(128 * 128 * 2);

    // 1. zero counts + W split/transpose (fused, independent halves)
    zero_cvtw_kernel<<<SCAN_NB + 64, 256, 0, stream>>>((int4*)counts, W1, Wmu, Wlog,
                                                       W1thi, W1tlo, Wcthi, Wctlo);
    // 2. CSR count + rank
    count_kernel<<<(E + 255) / 256, 256, 0, stream>>>(dst, counts, rank, E);
    // 3. local scan (padded) + dinv
    scan_local_kernel<<<SCAN_NB, 256, 0, stream>>>(counts, local, bsums, dinv);
    // 4. offsets + pad sentinels + zero sentinel rows
    scan_add_kernel<<<SCAN_NB, 256, 0, stream>>>(local, bsums, counts, offsets,
                                                 csr_src, xb, Hb);
    // 5. scatter + cvt_x (fused)
    {
        int scb = (E + 255) / 256;
        int cvb = (N * FDIM / 4 + 255) / 256;
        scatter_cvtx_kernel<<<scb + cvb, 256, 0, stream>>>(src, dst, rank, offsets,
                                                           csr_src, E, scb,
                                                           x, dinv, xb, N * FDIM / 4);
    }
    // 6. agg1 (column-split, L2-resident per colgroup)
    int nbg = (N + 15) / 16;
    agg_bf16_col_kernel<<<nbg * 4, 256, 0, stream>>>(xb, offsets, csr_src, dinv, Ag, N, nbg);
    // 7. Hb = bf16(dinv * relu((Ax) @ W1 + b1))
    mfma_gemm_kernel<0><<<(N + 127) / 128, 512, 0, stream>>>(Ag, W1thi, W1tlo,
                                                             b1, nullptr, dinv, Hb, nullptr, N);
    // 8. agg2 (column-split)
    agg_bf16_col_kernel<<<nbg * 4, 256, 0, stream>>>(Hb, offsets, csr_src, dinv, Ag, N, nbg);
    // 9. [mu | logstd] = (Ah) @ [Wmu|Wlog] + bias -> d_out
    mfma_gemm_kernel<1><<<(N + 127) / 128, 512, 0, stream>>>(Ag, Wcthi, Wctlo,
                                                             bmu, blog, nullptr, nullptr, out, N);
}

// Round 14
// 150.516 us; speedup vs baseline: 1.1466x; 1.1466x over previous
//
#include <hip/hip_runtime.h>
#include <hip/hip_bf16.h>

#define N_NODES 50000
#define FDIM 128
#define NPAD 50176      // 49 * 1024, covers N_NODES+1
#define SCAN_NB 49

typedef short bf16x8 __attribute__((ext_vector_type(8)));
typedef float f32x4  __attribute__((ext_vector_type(4)));

__device__ __forceinline__ unsigned short rne_bf16(float f) {
    unsigned int u = __float_as_uint(f);
    unsigned int r = (u + 0x7FFFu + ((u >> 16) & 1u)) >> 16;
    return (unsigned short)r;
}
__device__ __forceinline__ float bf16_to_f32(unsigned short s) {
    return __uint_as_float(((unsigned int)s) << 16);
}
__device__ __forceinline__ void split_bf16(float f, unsigned short& h, unsigned short& l) {
    h = rne_bf16(f);
    l = rne_bf16(f - bf16_to_f32(h));
}
__device__ __forceinline__ void unpack2(unsigned int d, float& f0, float& f1) {
    f0 = __uint_as_float(d << 16);
    f1 = __uint_as_float(d & 0xFFFF0000u);
}
// a[0..7] += row(m)  (8 bf16 in a uint4) -- pure add, weights pre-applied
__device__ __forceinline__ void add_row(const uint4& m, float* a) {
    float f0, f1;
    unpack2(m.x, f0, f1); a[0] += f0; a[1] += f1;
    unpack2(m.y, f0, f1); a[2] += f0; a[3] += f1;
    unpack2(m.z, f0, f1); a[4] += f0; a[5] += f1;
    unpack2(m.w, f0, f1); a[6] += f0; a[7] += f1;
}

// ---------------------------------------------------------------------------
// Fused: blocks [0,49) zero counts; blocks [49,113) split/transpose W
// (pre-swizzled idx ^= (n&7)<<3 for LDS bank-conflict-free reads)
// ---------------------------------------------------------------------------
__global__ __launch_bounds__(256) void zero_cvtw_kernel(int4* __restrict__ counts4,
                                                        const float* __restrict__ W1,
                                                        const float* __restrict__ Wmu,
                                                        const float* __restrict__ Wlog,
                                                        unsigned short* __restrict__ W1thi,
                                                        unsigned short* __restrict__ W1tlo,
                                                        unsigned short* __restrict__ Wcthi,
                                                        unsigned short* __restrict__ Wctlo) {
    int b = blockIdx.x;
    if (b < SCAN_NB) {
        int i = b * 256 + threadIdx.x;
        if (i < NPAD / 4) counts4[i] = make_int4(0, 0, 0, 0);
        return;
    }
    int tid = (b - SCAN_NB) * 256 + threadIdx.x;   // 0..16383
    int n = tid & 127, k = tid >> 7;
    int swzidx = (n * 128 + k) ^ ((n & 7) << 3);
    unsigned short h, l;
    float v1 = W1[k * 128 + n];
    split_bf16(v1, h, l);
    W1thi[swzidx] = h;
    W1tlo[swzidx] = l;
    float v2 = (n < 64) ? Wmu[k * 64 + n] : Wlog[k * 64 + (n - 64)];
    split_bf16(v2, h, l);
    Wcthi[swzidx] = h;
    Wctlo[swzidx] = l;
}

// CSR build: count in-degree AND capture each edge's rank within its dst
__global__ __launch_bounds__(256) void count_kernel(const int* __restrict__ dst,
                                                    int* __restrict__ counts,
                                                    int* __restrict__ rank, int E) {
    int e = blockIdx.x * blockDim.x + threadIdx.x;
    if (e < E) rank[e] = atomicAdd(&counts[dst[e]], 1);
}

// local scan over PADDED counts ((c+3)&~3) + dinv (0 for idx >= N)
__global__ __launch_bounds__(256) void scan_local_kernel(const int* __restrict__ counts,
                                                         int* __restrict__ local,
                                                         int* __restrict__ bsums,
                                                         float* __restrict__ dinv) {
    int t    = threadIdx.x;
    int lane = t & 63;
    int wid  = t >> 6;
    int base = blockIdx.x * 1024 + t * 4;
    int4 c = *(const int4*)(counts + base);
    float4 dv;
    dv.x = (base + 0 < N_NODES) ? rsqrtf((float)c.x + 1.0f) : 0.f;
    dv.y = (base + 1 < N_NODES) ? rsqrtf((float)c.y + 1.0f) : 0.f;
    dv.z = (base + 2 < N_NODES) ? rsqrtf((float)c.z + 1.0f) : 0.f;
    dv.w = (base + 3 < N_NODES) ? rsqrtf((float)c.w + 1.0f) : 0.f;
    *(float4*)(dinv + base) = dv;
    int4 v;   // padded counts
    v.x = (c.x + 3) & ~3;
    v.y = (c.y + 3) & ~3;
    v.z = (c.z + 3) & ~3;
    v.w = (c.w + 3) & ~3;
    int s = v.x + v.y + v.z + v.w;
    int incl = s;
#pragma unroll
    for (int off = 1; off < 64; off <<= 1) {
        int u = __shfl_up(incl, off, 64);
        if (lane >= off) incl += u;
    }
    __shared__ int wtot[4];
    if (lane == 63) wtot[wid] = incl;
    __syncthreads();
    int wbase = 0;
#pragma unroll
    for (int w = 0; w < 3; w++) wbase += (w < wid) ? wtot[w] : 0;
    int excl = wbase + incl - s;
    int4 o;
    o.x = excl;
    o.y = excl + v.x;
    o.z = o.y + v.y;
    o.w = o.z + v.z;
    *(int4*)(local + base) = o;
    if (t == 255) bsums[blockIdx.x] = wbase + incl;
}

// fused: bsums wave-scan + add block offset + write offsets + fill CSR pad
// slots with sentinel N_NODES + zero sentinel rows of xb/Hb (block 0)
__global__ __launch_bounds__(256) void scan_add_kernel(const int* __restrict__ local,
                                                       const int* __restrict__ bsums,
                                                       const int* __restrict__ counts,
                                                       int* __restrict__ offsets,
                                                       int* __restrict__ csr_src,
                                                       unsigned short* __restrict__ xb,
                                                       unsigned short* __restrict__ Hb) {
    int t = threadIdx.x;
    __shared__ int s_bo;
    if (t < 64) {
        int v = (t < blockIdx.x) ? bsums[t] : 0;   // blockIdx <= 48 < 64
#pragma unroll
        for (int off = 32; off; off >>= 1) v += __shfl_down(v, off, 64);
        if (t == 0) s_bo = v;
    }
    // zero sentinel row N of xb and Hb (128 ushorts = 64 uints each)
    if (blockIdx.x == 0 && t >= 64 && t < 128) {
        int k = t - 64;
        ((unsigned int*)(xb + (size_t)N_NODES * 128))[k] = 0u;
        ((unsigned int*)(Hb + (size_t)N_NODES * 128))[k] = 0u;
    }
    __syncthreads();
    int bo = s_bo;
    int base = blockIdx.x * 1024 + t * 4;
    int4 v = *(const int4*)(local + base);
    int4 c = *(const int4*)(counts + base);
    v.x += bo; v.y += bo; v.z += bo; v.w += bo;
    *(int4*)(offsets + base) = v;
    // pad fill: slots [off + count, off + paddedcount) = sentinel
    int off0[4] = {v.x, v.y, v.z, v.w};
    int cr[4]   = {c.x, c.y, c.z, c.w};
#pragma unroll
    for (int k = 0; k < 4; k++) {
        int b = off0[k] + cr[k];
        int e = off0[k] + ((cr[k] + 3) & ~3);
        for (int j = b; j < e; j++) csr_src[j] = N_NODES;
    }
}

// ---------------------------------------------------------------------------
// Fused: blocks [0,scb) atomic-free scatter; blocks [scb, scb+cvb) cvt_x
// (xs = dinv[row]*x, single bf16 rounding)
// ---------------------------------------------------------------------------
__global__ __launch_bounds__(256) void scatter_cvtx_kernel(const int* __restrict__ src,
                                                           const int* __restrict__ dst,
                                                           const int* __restrict__ rank,
                                                           const int* __restrict__ offsets,
                                                           int* __restrict__ csr_src, int E,
                                                           int scb,
                                                           const float* __restrict__ x,
                                                           const float* __restrict__ dinv,
                                                           unsigned short* __restrict__ xb,
                                                           int n4) {
    int b = blockIdx.x;
    if (b < scb) {
        int e = b * 256 + threadIdx.x;
        if (e < E) {
            int d = dst[e];
            int pos = offsets[d] + rank[e];
            csr_src[pos] = src[e];
        }
        return;
    }
    int i = (b - scb) * 256 + threadIdx.x;
    if (i >= n4) return;
    float dv = dinv[i >> 5];   // 32 float4 per row
    float4 v = ((const float4*)x)[i];
    v.x *= dv; v.y *= dv; v.z *= dv; v.w *= dv;
    unsigned int d0 = (unsigned int)rne_bf16(v.x) | ((unsigned int)rne_bf16(v.y) << 16);
    unsigned int d1 = (unsigned int)rne_bf16(v.z) | ((unsigned int)rne_bf16(v.w) << 16);
    ((uint2*)xb)[i] = make_uint2(d0, d1);
}

// ---------------------------------------------------------------------------
// Aggregation: pure row-sum of pre-scaled bf16 rows, final *dinv[node].
// Quarter-wave (16 lanes x 16B) per node; int4 index loads (CSR 4-padded,
// sentinel row N_NODES is all-zero). Output: SINGLE bf16 plane.
// ---------------------------------------------------------------------------
__global__ __launch_bounds__(256) void agg_bf16_kernel(const unsigned short* __restrict__ X,
                                                       const int* __restrict__ offsets,
                                                       const int* __restrict__ csr_src,
                                                       const float* __restrict__ dinv,
                                                       unsigned short* __restrict__ Y,
                                                       int n) {
    int node = (blockIdx.x << 4) + (threadIdx.x >> 4);
    int l16  = threadIdx.x & 15;
    if (node >= n) return;
    const uint4* X16 = (const uint4*)X;

    float a[8];
    {
        uint4 xv = X16[(size_t)node * 16 + l16];   // self row (pre-scaled)
        float f0, f1;
        unpack2(xv.x, f0, f1); a[0] = f0; a[1] = f1;
        unpack2(xv.y, f0, f1); a[2] = f0; a[3] = f1;
        unpack2(xv.z, f0, f1); a[4] = f0; a[5] = f1;
        unpack2(xv.w, f0, f1); a[6] = f0; a[7] = f1;
    }

    int beg = offsets[node], end = offsets[node + 1];
    int i = beg;
    for (; i + 8 <= end; i += 8) {
        int4 q0 = *(const int4*)(csr_src + i);
        int4 q1 = *(const int4*)(csr_src + i + 4);
        uint4 m0 = X16[(size_t)q0.x * 16 + l16];
        uint4 m1 = X16[(size_t)q0.y * 16 + l16];
        uint4 m2 = X16[(size_t)q0.z * 16 + l16];
        uint4 m3 = X16[(size_t)q0.w * 16 + l16];
        uint4 m4 = X16[(size_t)q1.x * 16 + l16];
        uint4 m5 = X16[(size_t)q1.y * 16 + l16];
        uint4 m6 = X16[(size_t)q1.z * 16 + l16];
        uint4 m7 = X16[(size_t)q1.w * 16 + l16];
        add_row(m0, a); add_row(m1, a); add_row(m2, a); add_row(m3, a);
        add_row(m4, a); add_row(m5, a); add_row(m6, a); add_row(m7, a);
    }
    if (i < end) {
        int4 q0 = *(const int4*)(csr_src + i);
        uint4 m0 = X16[(size_t)q0.x * 16 + l16];
        uint4 m1 = X16[(size_t)q0.y * 16 + l16];
        uint4 m2 = X16[(size_t)q0.z * 16 + l16];
        uint4 m3 = X16[(size_t)q0.w * 16 + l16];
        add_row(m0, a); add_row(m1, a); add_row(m2, a); add_row(m3, a);
    }

    float dv = dinv[node];
    unsigned short h[8];
#pragma unroll
    for (int j = 0; j < 8; j++) h[j] = rne_bf16(a[j] * dv);
    uint4 ph;
    ph.x = (unsigned int)h[0] | ((unsigned int)h[1] << 16);
    ph.y = (unsigned int)h[2] | ((unsigned int)h[3] << 16);
    ph.z = (unsigned int)h[4] | ((unsigned int)h[5] << 16);
    ph.w = (unsigned int)h[6] | ((unsigned int)h[7] << 16);
    ((uint4*)Y)[(size_t)node * 16 + l16] = ph;
}

// ---------------------------------------------------------------------------
// MFMA GEMM, W-in-LDS: 512 threads / 8 waves / 128 rows per block.
// A single bf16; W hi/lo split -> D = A*Wh + A*Wl (fp32 accumulate).
// EPI 0: Hb = bf16(dinv[r] * relu(D + b1))   (pre-scaled for agg2)
// EPI 1: split mu/logstd halves to out.
// ---------------------------------------------------------------------------
template <int EPI>
__global__ __launch_bounds__(512) void mfma_gemm_kernel(const unsigned short* __restrict__ A,
                                                        const unsigned short* __restrict__ Wthi,
                                                        const unsigned short* __restrict__ Wtlo,
                                                        const float* __restrict__ ba,
                                                        const float* __restrict__ bb,
                                                        const float* __restrict__ dinv,
                                                        unsigned short* __restrict__ H,
                                                        float* __restrict__ out, int M) {
    __shared__ unsigned short Wlds[32768];   // hi [0,16K) ushorts, lo [16K,32K)

    int t    = threadIdx.x;
    int wave = t >> 6;
    int lane = t & 63;
    int m16  = lane & 15;
    int kg   = lane >> 4;

    // stage W (linear; source is pre-swizzled). 4096 uint4 / 512 threads.
    {
        const uint4* gh = (const uint4*)Wthi;
        const uint4* gl = (const uint4*)Wtlo;
        uint4* lds4 = (uint4*)Wlds;
#pragma unroll
        for (int i = 0; i < 4; i++) lds4[i * 512 + t] = gh[i * 512 + t];
#pragma unroll
        for (int i = 0; i < 4; i++) lds4[2048 + i * 512 + t] = gl[i * 512 + t];
    }

    int rbase = blockIdx.x * 128 + wave * 16;
    int arow  = rbase + m16;
    bool rok  = arow < M;
    const unsigned short* ar = A + (size_t)(rok ? arow : 0) * 128;
    bf16x8 af[4];
#pragma unroll
    for (int kt = 0; kt < 4; kt++) {
        bf16x8 v = *(const bf16x8*)(const void*)(ar + kt * 32 + kg * 8);
        af[kt] = rok ? v : (bf16x8)(short)0;
    }
    // per-lane output rows are rbase+kg*4+0..3 for all col tiles; hoist dinv
    float4 dv4 = {1.f, 1.f, 1.f, 1.f};
    if (EPI == 0) dv4 = *(const float4*)(dinv + rbase + kg * 4);
    __syncthreads();

    int swz = (m16 & 7) << 3;
#pragma unroll
    for (int np = 0; np < 4; np++) {
        int nt0 = np * 2, nt1 = np * 2 + 1;
        f32x4 acc0 = {0.f, 0.f, 0.f, 0.f};
        f32x4 acc1 = {0.f, 0.f, 0.f, 0.f};
#pragma unroll
        for (int kt = 0; kt < 4; kt++) {
            int i0 = (((nt0 * 16 + m16) * 128) + kt * 32 + kg * 8) ^ swz;
            int i1 = (((nt1 * 16 + m16) * 128) + kt * 32 + kg * 8) ^ swz;
            bf16x8 bh0 = *(const bf16x8*)(const void*)&Wlds[i0];
            bf16x8 bl0 = *(const bf16x8*)(const void*)&Wlds[16384 + i0];
            bf16x8 bh1 = *(const bf16x8*)(const void*)&Wlds[i1];
            bf16x8 bl1 = *(const bf16x8*)(const void*)&Wlds[16384 + i1];
            acc0 = __builtin_amdgcn_mfma_f32_16x16x32_bf16(af[kt], bh0, acc0, 0, 0, 0);
            acc1 = __builtin_amdgcn_mfma_f32_16x16x32_bf16(af[kt], bh1, acc1, 0, 0, 0);
            acc0 = __builtin_amdgcn_mfma_f32_16x16x32_bf16(af[kt], bl0, acc0, 0, 0, 0);
            acc1 = __builtin_amdgcn_mfma_f32_16x16x32_bf16(af[kt], bl1, acc1, 0, 0, 0);
        }
#pragma unroll
        for (int half = 0; half < 2; half++) {
            int nt = half ? nt1 : nt0;
            const f32x4& acc = half ? acc1 : acc0;
            int n0 = nt * 16 + m16;
            if (EPI == 0) {
                float b = ba[n0];
#pragma unroll
                for (int j = 0; j < 4; j++) {
                    int r = rbase + kg * 4 + j;
                    if (r < M) {
                        float v = fmaxf(acc[j] + b, 0.f) * dv4[j];
                        H[(size_t)r * 128 + n0] = rne_bf16(v);
                    }
                }
            } else {
                bool is_mu = (n0 < 64);
                int c = is_mu ? n0 : (n0 - 64);
                float b = is_mu ? ba[c] : bb[c];
                size_t obase = is_mu ? 0 : (size_t)N_NODES * 64;
#pragma unroll
                for (int j = 0; j < 4; j++) {
                    int r = rbase + kg * 4 + j;
                    if (r < M) out[obase + (size_t)r * 64 + c] = acc[j] + b;
                }
            }
        }
    }
}

// ---------------------------------------------------------------------------
extern "C" void kernel_launch(void* const* d_in, const int* in_sizes, int n_in,
                              void* d_out, int out_size, void* d_ws, size_t ws_size,
                              hipStream_t stream) {
    const float* x    = (const float*)d_in[0];
    const int*   ei   = (const int*)d_in[1];
    const float* W1   = (const float*)d_in[2];
    const float* b1   = (const float*)d_in[3];
    const float* Wmu  = (const float*)d_in[4];
    const float* bmu  = (const float*)d_in[5];
    const float* Wlog = (const float*)d_in[6];
    const float* blog = (const float*)d_in[7];
    float* out = (float*)d_out;

    const int N = N_NODES;
    const int E = in_sizes[1] / 2;
    const int Emax = E + 3 * N;   // CSR with 4-padding slack
    const int* src = ei;
    const int* dst = ei + E;

    auto align256 = [](size_t v) { return (v + 255) & ~(size_t)255; };
    char* ws = (char*)d_ws;
    size_t off = 0;
    int*   counts  = (int*)(ws + off);  off += align256((size_t)NPAD * 4);
    int*   offsets = (int*)(ws + off);  off += align256((size_t)NPAD * 4);
    int*   local   = (int*)(ws + off);  off += align256((size_t)NPAD * 4);
    int*   bsums   = (int*)(ws + off);  off += align256(256 * 4);
    float* dinv    = (float*)(ws + off); off += align256((size_t)NPAD * 4);
    int*   rank    = (int*)(ws + off);  off += align256((size_t)E * 4);
    int*   csr_src = (int*)(ws + off);  off += align256((size_t)Emax * 4);
    unsigned short* xb    = (unsigned short*)(ws + off); off += align256((size_t)(N + 1) * FDIM * 2);
    unsigned short* Hb    = (unsigned short*)(ws + off); off += align256((size_t)(N + 1) * FDIM * 2);
    unsigned short* Ag    = (unsigned short*)(ws + off); off += align256((size_t)N * FDIM * 2);
    unsigned short* W1thi = (unsigned short*)(ws + off); off += align256(128 * 128 * 2);
    unsigned short* W1tlo = (unsigned short*)(ws + off); off += align256(128 * 128 * 2);
    unsigned short* Wcthi = (unsigned short*)(ws + off); off += align256(128 * 128 * 2);
    unsigned short* Wctlo = (unsigned short*)(ws + off); off += align256(128 * 128 * 2);

    // 1. zero counts + W split/transpose (fused, independent halves)
    zero_cvtw_kernel<<<SCAN_NB + 64, 256, 0, stream>>>((int4*)counts, W1, Wmu, Wlog,
                                                       W1thi, W1tlo, Wcthi, Wctlo);
    // 2. CSR count + rank
    count_kernel<<<(E + 255) / 256, 256, 0, stream>>>(dst, counts, rank, E);
    // 3. local scan (padded) + dinv
    scan_local_kernel<<<SCAN_NB, 256, 0, stream>>>(counts, local, bsums, dinv);
    // 4. offsets + pad sentinels + zero sentinel rows
    scan_add_kernel<<<SCAN_NB, 256, 0, stream>>>(local, bsums, counts, offsets,
                                                 csr_src, xb, Hb);
    // 5. scatter + cvt_x (fused)
    {
        int scb = (E + 255) / 256;
        int cvb = (N * FDIM / 4 + 255) / 256;
        scatter_cvtx_kernel<<<scb + cvb, 256, 0, stream>>>(src, dst, rank, offsets,
                                                           csr_src, E, scb,
                                                           x, dinv, xb, N * FDIM / 4);
    }
    // 6. agg1: dv*(xs_v + sum xs_s) -> single bf16
    agg_bf16_kernel<<<(N + 15) / 16, 256, 0, stream>>>(xb, offsets, csr_src, dinv, Ag, N);
    // 7. Hb = bf16(dinv * relu((Ax) @ W1 + b1))
    mfma_gemm_kernel<0><<<(N + 127) / 128, 512, 0, stream>>>(Ag, W1thi, W1tlo,
                                                             b1, nullptr, dinv, Hb, nullptr, N);
    // 8. agg2: dv*(hs_v + sum hs_s) -> single bf16
    agg_bf16_kernel<<<(N + 15) / 16, 256, 0, stream>>>(Hb, offsets, csr_src, dinv, Ag, N);
    // 9. [mu | logstd] = (Ah) @ [Wmu|Wlog] + bias -> d_out
    mfma_gemm_kernel<1><<<(N + 127) / 128, 512, 0, stream>>>(Ag, Wcthi, Wctlo,
                                                             bmu, blog, nullptr, nullptr, out, N);
}